// Round 5
// baseline (1541.589 us; speedup 1.0000x reference)
//
#include <hip/hip_runtime.h>
#include <math.h>

#define D 768
#define DF4 192      // D/4
#define SEQ 128
#define TN 256       // docs per block tile
#define NCHUNK 24    // 768/32 floats per chunk per doc
#define NBK 64       // top-k blocks per row
#define TOPK 10

// ---------------- K1: mean over sequence ----------------
__global__ __launch_bounds__(256) void k_mean(const float* __restrict__ q,
                                              float* __restrict__ qmean) {
  int d = blockIdx.x * 256 + threadIdx.x;   // grid.x = 3 -> 768
  int b = blockIdx.y;
  if (d >= D) return;
  const float* p = q + (long)b * SEQ * D + d;
  float s = 0.f;
  #pragma unroll 8
  for (int i = 0; i < SEQ; ++i) s += p[(long)i * D];
  qmean[b * D + d] = s * (1.0f / SEQ);
}

// ---------------- K2: projection + bias + L2 normalize ----------------
__global__ __launch_bounds__(256) void k_proj(const float* __restrict__ qmean,
                                              const float* __restrict__ W,
                                              const float* __restrict__ bias,
                                              float* __restrict__ qnorm) {
  __shared__ float4 qm[DF4];
  __shared__ float red[256];
  int b = blockIdx.x, t = threadIdx.x;
  for (int i = t; i < DF4; i += 256) qm[i] = ((const float4*)qmean)[b * DF4 + i];
  __syncthreads();
  float myout[3];
  #pragma unroll
  for (int i = 0; i < 3; ++i) {
    int j = t + i * 256;
    const float4* wr = (const float4*)W + (long)j * DF4;
    float a0 = 0.f, a1 = 0.f, a2 = 0.f, a3 = 0.f;
    for (int kk = 0; kk < DF4; ++kk) {
      float4 w = wr[kk]; float4 qv = qm[kk];
      a0 = fmaf(w.x, qv.x, a0); a1 = fmaf(w.y, qv.y, a1);
      a2 = fmaf(w.z, qv.z, a2); a3 = fmaf(w.w, qv.w, a3);
    }
    myout[i] = (a0 + a1) + (a2 + a3) + bias[j];
  }
  float ss = myout[0]*myout[0] + myout[1]*myout[1] + myout[2]*myout[2];
  red[t] = ss;
  __syncthreads();
  for (int h = 128; h > 0; h >>= 1) {
    if (t < h) red[t] += red[t + h];
    __syncthreads();
  }
  float rn = 1.0f / fmaxf(sqrtf(red[0]), 1e-12f);
  #pragma unroll
  for (int i = 0; i < 3; ++i) {
    int j = t + i * 256;
    qnorm[b * D + j] = myout[i] * rn;
  }
}

// ---------------- K3: cosine scores (the big one) ----------------
// STRUCTURAL REDESIGN to fit the toolchain's 64-VGPR pin (measured r1/r3/r4:
// __launch_bounds__(256,{4,3,2}) all allocate 64 VGPRs; any live state above
// that spills — r3/r4 WRITE_SIZE showed exactly the r[8] buffer (1.47 GB)
// round-tripping scratch).
//
// 1) No register staging: global->LDS via __builtin_amdgcn_global_load_lds
//    (width 16). LDS layout [doc 256][kq 8] float4, with the kq slot XOR-
//    permuted by (doc&7). Permutation applied on the SOURCE address at stage
//    time and on the READ address (both-sides); DMA destination is linear
//    (wave-uniform base + lane*16). Staging is fully coalesced: each wave
//    instruction covers 1 KB contiguous (8 docs x 128 B, permuted within
//    rows). Reads are 2-way bank-aliased = free (m136).
// 2) Wave owns 64 docs x ALL 32 q rows; lane <-> one doc. acc[32] VGPRs,
//    ssq scalar, dv one float4 at a time. q addresses are fully uniform
//    (qi,kq,c loop constants) -> s_load into SGPRs, scalar pipe.
// Live VGPRs ~56 < 64 -> no spill. Overlap via ~5 blocks/CU (32 KB LDS).
__global__ __launch_bounds__(256) void k_scores(const float* __restrict__ docs,
                                                const float* __restrict__ qn,
                                                float* __restrict__ outS, int N) {
  __shared__ float4 lds[TN * 8];   // 32 KB: [doc][kq^(doc&7)]
  const int t = threadIdx.x;
  const int l = t & 63;
  const int w = t >> 6;
  const int pl = l & 7;            // position within 8-lane group
  const int gl = l >> 3;           // group within wave
  const int kq_src = pl ^ gl;      // source kq this lane stages (doc&7 == gl)
  const long tile0 = (long)blockIdx.x * TN;
  const int wbyte = __builtin_amdgcn_readfirstlane(w << 10);  // wave LDS base
  const char* docsb = (const char*)docs;
  const float4* qn4 = (const float4*)qn;

  // Per-thread stage source byte-bases (c-independent, clamped for tail).
  // Thread (w,gl,pl), issue j stages doc (w*8+gl+j*32), f4 slot kq_src.
  unsigned bstage[8];
  #pragma unroll
  for (int j = 0; j < 8; ++j) {
    long dcl = tile0 + (w * 8 + gl) + j * 32;
    if (dcl >= N) dcl = N - 1;
    bstage[j] = (unsigned)(dcl * (D * 4)) + (unsigned)(kq_src * 16);
  }

  float acc[32];
  #pragma unroll
  for (int i = 0; i < 32; ++i) acc[i] = 0.f;
  float ssq = 0.f;

  #pragma unroll 1
  for (int c = 0; c < NCHUNK; ++c) {
    __syncthreads();                       // chunk c-1 consumers done
    #pragma unroll
    for (int j = 0; j < 8; ++j) {          // DMA chunk c: 32 KB, no VGPR staging
      const void* g = (const void*)(docsb + (bstage[j] + (unsigned)(c * 128)));
      void* lp = (void*)((char*)lds + (j * 4096 + wbyte));
      __builtin_amdgcn_global_load_lds(
          (const __attribute__((address_space(1))) void*)g,
          (__attribute__((address_space(3))) void*)lp, 16, 0, 0);
    }
    __syncthreads();                       // vmcnt(0) drained before barrier
    #pragma unroll
    for (int kq = 0; kq < 8; ++kq) {
      float4 dv = lds[t * 8 + (kq ^ (t & 7))];   // lane's own doc row
      ssq = fmaf(dv.x, dv.x, ssq);
      ssq = fmaf(dv.y, dv.y, ssq);
      ssq = fmaf(dv.z, dv.z, ssq);
      ssq = fmaf(dv.w, dv.w, ssq);
      #pragma unroll
      for (int qi = 0; qi < 32; ++qi) {
        float4 q4 = qn4[qi * DF4 + c * 8 + kq];  // uniform -> s_load (SGPRs)
        acc[qi] = fmaf(q4.x, dv.x, acc[qi]);
        acc[qi] = fmaf(q4.y, dv.y, acc[qi]);
        acc[qi] = fmaf(q4.z, dv.z, acc[qi]);
        acc[qi] = fmaf(q4.w, dv.w, acc[qi]);
      }
    }
  }

  long gd = tile0 + t;                     // lane's doc
  if (gd < N) {
    float rn = 1.0f / fmaxf(sqrtf(ssq), 1e-12f);
    #pragma unroll
    for (int qi = 0; qi < 32; ++qi)
      outS[(long)qi * N + gd] = acc[qi] * rn;   // coalesced across lanes
  }
}

// ---------------- top-k helpers ----------------
// ranks-before comparator: higher score wins; tie -> smaller index (lax.top_k stable)
__device__ __forceinline__ void insert10(float v, float p, float bs[10], float bi[10]) {
  bool last = (v > bs[9]) || (v == bs[9] && p < bi[9]);
  if (!last) return;
  #pragma unroll
  for (int j = 9; j >= 1; --j) {     // static indices only (no scratch)
    bool bj  = (v > bs[j])   || (v == bs[j]   && p < bi[j]);
    bool bjm = (v > bs[j-1]) || (v == bs[j-1] && p < bi[j-1]);
    float ns = bj ? (bjm ? bs[j-1] : v) : bs[j];
    float ni = bj ? (bjm ? bi[j-1] : p) : bi[j];
    bs[j] = ns; bi[j] = ni;
  }
  bool b0 = (v > bs[0]) || (v == bs[0] && p < bi[0]);
  if (b0) { bs[0] = v; bi[0] = p; }
}

// ---------------- K4: per-(row, segment) top-10 ----------------
__global__ __launch_bounds__(256) void k_topblk(const float* __restrict__ scores,
                                                float2* __restrict__ btop, int N) {
  const int row = blockIdx.y, seg = blockIdx.x, t = threadIdx.x;
  const int per = (N + NBK - 1) / NBK;
  const int s0 = seg * per;
  const int s1 = (s0 + per < N) ? (s0 + per) : N;
  const float* rp = scores + (long)row * N;
  float bs[10], bi[10];
  #pragma unroll
  for (int k = 0; k < 10; ++k) { bs[k] = -INFINITY; bi[k] = 2.0e9f; }
  for (int p = s0 + t; p < s1; p += 256) insert10(rp[p], (float)p, bs, bi);

  __shared__ float ms[256][10];
  __shared__ float mi[256][10];
  #pragma unroll
  for (int k = 0; k < 10; ++k) { ms[t][k] = bs[k]; mi[t][k] = bi[k]; }
  __syncthreads();
  for (int h = 128; h > 0; h >>= 1) {
    if (t < h) {
      float os[10], oi[10];
      int x = 0, y = 0;
      #pragma unroll
      for (int k = 0; k < 10; ++k) {
        float sx = ms[t][x], sy = ms[t + h][y];
        float ix = mi[t][x], iy = mi[t + h][y];
        bool ta = (sx > sy) || (sx == sy && ix < iy);
        os[k] = ta ? sx : sy; oi[k] = ta ? ix : iy;
        x += ta ? 1 : 0; y += ta ? 0 : 1;
      }
      #pragma unroll
      for (int k = 0; k < 10; ++k) { ms[t][k] = os[k]; mi[t][k] = oi[k]; }
    }
    __syncthreads();
  }
  if (t == 0) {
    #pragma unroll
    for (int k = 0; k < 10; ++k)
      btop[((long)row * NBK + seg) * 10 + k] = make_float2(ms[0][k], mi[0][k]);
  }
}

// ---------------- K5: final merge per row, write indices as float ----------------
__global__ __launch_bounds__(256) void k_topfinal(const float2* __restrict__ btop,
                                                  float* __restrict__ outIdx) {
  const int row = blockIdx.x, t = threadIdx.x;
  const int M = NBK * 10;   // 640 candidates
  float bs[10], bi[10];
  #pragma unroll
  for (int k = 0; k < 10; ++k) { bs[k] = -INFINITY; bi[k] = 2.0e9f; }
  for (int p = t; p < M; p += 256) {
    float2 c = btop[(long)row * M + p];
    insert10(c.x, c.y, bs, bi);
  }
  __shared__ float ms[256][10];
  __shared__ float mi[256][10];
  #pragma unroll
  for (int k = 0; k < 10; ++k) { ms[t][k] = bs[k]; mi[t][k] = bi[k]; }
  __syncthreads();
  for (int h = 128; h > 0; h >>= 1) {
    if (t < h) {
      float os[10], oi[10];
      int x = 0, y = 0;
      #pragma unroll
      for (int k = 0; k < 10; ++k) {
        float sx = ms[t][x], sy = ms[t + h][y];
        float ix = mi[t][x], iy = mi[t + h][y];
        bool ta = (sx > sy) || (sx == sy && ix < iy);
        os[k] = ta ? sx : sy; oi[k] = ta ? ix : iy;
        x += ta ? 1 : 0; y += ta ? 0 : 1;
      }
      #pragma unroll
      for (int k = 0; k < 10; ++k) { ms[t][k] = os[k]; mi[t][k] = oi[k]; }
    }
    __syncthreads();
  }
  if (t == 0) {
    #pragma unroll
    for (int k = 0; k < 10; ++k) outIdx[row * TOPK + k] = mi[0][k];
  }
}

extern "C" void kernel_launch(void* const* d_in, const int* in_sizes, int n_in,
                              void* d_out, int out_size, void* d_ws, size_t ws_size,
                              hipStream_t stream) {
  const float* q    = (const float*)d_in[0];   // [32,128,768]
  const float* docs = (const float*)d_in[1];   // [N,768]
  const float* W    = (const float*)d_in[2];   // [768,768]
  const float* bias = (const float*)d_in[3];   // [768]
  const int B = in_sizes[0] / (SEQ * D);       // 32
  const int N = in_sizes[1] / D;               // 500000

  float* out    = (float*)d_out;
  float* outIdx = out;                          // [B*10] indices as float
  float* outS   = out + (long)B * TOPK;         // [B][N] scores

  float*  qmean = (float*)d_ws;                 // B*D
  float*  qnorm = qmean + (long)B * D;          // B*D
  float2* btop  = (float2*)(qnorm + (long)B * D); // B*NBK*10 pairs

  dim3 g1(3, B);
  k_mean<<<g1, 256, 0, stream>>>(q, qmean);
  k_proj<<<B, 256, 0, stream>>>(qmean, W, bias, qnorm);
  int ntiles = (N + TN - 1) / TN;
  k_scores<<<ntiles, 256, 0, stream>>>(docs, qnorm, outS, N);
  dim3 g4(NBK, B);
  k_topblk<<<g4, 256, 0, stream>>>(outS, btop, N);
  k_topfinal<<<B, 256, 0, stream>>>(btop, outIdx);
}

// Round 6
// 639.350 us; speedup vs baseline: 2.4112x; 2.4112x over previous
//
#include <hip/hip_runtime.h>
#include <math.h>

#define D 768
#define DF4 192      // D/4
#define SEQ 128
#define TN 256       // docs per block tile
#define NCHUNK 24    // 768/32 floats per chunk per doc
#define NBK 64       // top-k blocks per row
#define TOPK 10

// ---------------- K1: mean over sequence ----------------
__global__ __launch_bounds__(256) void k_mean(const float* __restrict__ q,
                                              float* __restrict__ qmean) {
  int d = blockIdx.x * 256 + threadIdx.x;   // grid.x = 3 -> 768
  int b = blockIdx.y;
  if (d >= D) return;
  const float* p = q + (long)b * SEQ * D + d;
  float s = 0.f;
  #pragma unroll 8
  for (int i = 0; i < SEQ; ++i) s += p[(long)i * D];
  qmean[b * D + d] = s * (1.0f / SEQ);
}

// ---------------- K2: projection + bias + L2 normalize ----------------
__global__ __launch_bounds__(256) void k_proj(const float* __restrict__ qmean,
                                              const float* __restrict__ W,
                                              const float* __restrict__ bias,
                                              float* __restrict__ qnorm) {
  __shared__ float4 qm[DF4];
  __shared__ float red[256];
  int b = blockIdx.x, t = threadIdx.x;
  for (int i = t; i < DF4; i += 256) qm[i] = ((const float4*)qmean)[b * DF4 + i];
  __syncthreads();
  float myout[3];
  #pragma unroll
  for (int i = 0; i < 3; ++i) {
    int j = t + i * 256;
    const float4* wr = (const float4*)W + (long)j * DF4;
    float a0 = 0.f, a1 = 0.f, a2 = 0.f, a3 = 0.f;
    for (int kk = 0; kk < DF4; ++kk) {
      float4 w = wr[kk]; float4 qv = qm[kk];
      a0 = fmaf(w.x, qv.x, a0); a1 = fmaf(w.y, qv.y, a1);
      a2 = fmaf(w.z, qv.z, a2); a3 = fmaf(w.w, qv.w, a3);
    }
    myout[i] = (a0 + a1) + (a2 + a3) + bias[j];
  }
  float ss = myout[0]*myout[0] + myout[1]*myout[1] + myout[2]*myout[2];
  red[t] = ss;
  __syncthreads();
  for (int h = 128; h > 0; h >>= 1) {
    if (t < h) red[t] += red[t + h];
    __syncthreads();
  }
  float rn = 1.0f / fmaxf(sqrtf(red[0]), 1e-12f);
  #pragma unroll
  for (int i = 0; i < 3; ++i) {
    int j = t + i * 256;
    qnorm[b * D + j] = myout[i] * rn;
  }
}

// ---------------- K3: cosine scores (the big one) ----------------
// r6 structure:
//  - Doc staging: global_load_lds DMA (r5-proven: kills the reg staging buffer
//    and its spill; WRITE_SIZE == mandatory). LDS [doc 256][slot 8] f4, slot
//    permuted by doc&7 on the SOURCE address; reads use the same XOR.
//  - q delivery: per-chunk q tile (32q x 8 f4 = 4KB) DMA'd to LDS; inner-loop
//    q reads are same-address wave BROADCASTS (conflict-free, DS pipe).
//    r3/r4/r5's scalar-q inner loop was the killer: s_load (SMEM) and ds_read
//    (LDS) share lgkmcnt and complete out-of-order -> per-use lgkmcnt(0)
//    drains, ~200cyc serialized per q4 (measured: 7.2% HBM, 71k cyc/chunk).
//    All-DS inner loop gets fine-grained in-order lgkmcnt(N).
//  - Work split: wave owns 8 q rows x 256 docs (4/lane): acc[8][4], q-reads
//    amortized over 4 docs -> 96 DS reads/thread/chunk.
//  - amdgpu_waves_per_eu(2,4): caps allocator's occupancy target at 4 waves/EU
//    (128-VGPR budget). launch_bounds(256,{2,3,4}) all pinned 64 VGPR and
//    spilled (r1/r3/r4); bare (256) allocated naturally (r5: 56).
__global__ __launch_bounds__(256) __attribute__((amdgpu_waves_per_eu(2, 4)))
void k_scores(const float* __restrict__ docs,
              const float* __restrict__ qn,
              float* __restrict__ outS, int N) {
  __shared__ float4 ldsD[TN * 8];   // 32 KB: [doc][kq ^ (doc&7)]
  __shared__ float4 ldsQ[32 * 8];   // 4 KB:  [qi][kq] linear
  const int t = threadIdx.x;
  const int l = t & 63;
  const int w = t >> 6;
  const int pl = l & 7;            // position within 8-lane group
  const int gl = l >> 3;           // group within wave
  const int kq_src = pl ^ gl;      // doc slot this lane stages (doc&7 == gl)
  const long tile0 = (long)blockIdx.x * TN;
  const int o8 = w * 8;            // wave's q base row
  const char* docsb = (const char*)docs;
  const char* qnb = (const char*)qn;

  // Doc-stage source byte-bases (c-independent, clamped for tail).
  // Thread (w,gl,pl), issue j stages doc (w*8+gl+j*32), f4 slot kq_src.
  unsigned bstage[8];
  #pragma unroll
  for (int j = 0; j < 8; ++j) {
    long dcl = tile0 + (w * 8 + gl) + j * 32;
    if (dcl >= N) dcl = N - 1;
    bstage[j] = (unsigned)(dcl * (D * 4)) + (unsigned)(kq_src * 16);
  }
  // q-stage source byte-base: q row (w*8+gl), slot pl (no permute needed:
  // q reads are uniform-address broadcasts -> never bank-conflict).
  const unsigned qsb = (unsigned)((w * 8 + gl) * (D * 4)) + (unsigned)(pl * 16);

  // Wave-uniform LDS dest bases (DMA dest = uniform base + lane*16).
  const int wbyteD = __builtin_amdgcn_readfirstlane(w << 10);
  const int wbyteQ = __builtin_amdgcn_readfirstlane(w << 10);

  float acc[8][4];
  #pragma unroll
  for (int i = 0; i < 8; ++i)
    #pragma unroll
    for (int j = 0; j < 4; ++j) acc[i][j] = 0.f;
  float ssq[4] = {0.f, 0.f, 0.f, 0.f};

  #pragma unroll 1
  for (int c = 0; c < NCHUNK; ++c) {
    __syncthreads();                       // chunk c-1 consumers done
    #pragma unroll
    for (int j = 0; j < 8; ++j) {          // DMA doc chunk c: 32 KB
      const void* g = (const void*)(docsb + (bstage[j] + (unsigned)(c * 128)));
      void* lp = (void*)((char*)ldsD + (j * 4096 + wbyteD));
      __builtin_amdgcn_global_load_lds(
          (const __attribute__((address_space(1))) void*)g,
          (__attribute__((address_space(3))) void*)lp, 16, 0, 0);
    }
    {                                      // DMA q chunk c: 4 KB (1 issue/wave)
      const void* g = (const void*)(qnb + (qsb + (unsigned)(c * 128)));
      void* lp = (void*)((char*)ldsQ + wbyteQ);
      __builtin_amdgcn_global_load_lds(
          (const __attribute__((address_space(1))) void*)g,
          (__attribute__((address_space(3))) void*)lp, 16, 0, 0);
    }
    __syncthreads();                       // vmcnt(0) drained before barrier
    #pragma unroll
    for (int kq = 0; kq < 8; ++kq) {
      float4 dv[4];
      #pragma unroll
      for (int dj = 0; dj < 4; ++dj) {
        dv[dj] = ldsD[(l + dj * 64) * 8 + (kq ^ (l & 7))];
        ssq[dj] = fmaf(dv[dj].x, dv[dj].x, ssq[dj]);
        ssq[dj] = fmaf(dv[dj].y, dv[dj].y, ssq[dj]);
        ssq[dj] = fmaf(dv[dj].z, dv[dj].z, ssq[dj]);
        ssq[dj] = fmaf(dv[dj].w, dv[dj].w, ssq[dj]);
      }
      #pragma unroll
      for (int qi = 0; qi < 8; ++qi) {
        float4 q4 = ldsQ[(o8 + qi) * 8 + kq];   // uniform addr -> broadcast
        #pragma unroll
        for (int dj = 0; dj < 4; ++dj) {
          acc[qi][dj] = fmaf(q4.x, dv[dj].x, acc[qi][dj]);
          acc[qi][dj] = fmaf(q4.y, dv[dj].y, acc[qi][dj]);
          acc[qi][dj] = fmaf(q4.z, dv[dj].z, acc[qi][dj]);
          acc[qi][dj] = fmaf(q4.w, dv[dj].w, acc[qi][dj]);
        }
      }
    }
  }

  #pragma unroll
  for (int dj = 0; dj < 4; ++dj) {
    long gd = tile0 + l + dj * 64;
    if (gd < N) {
      float rn = 1.0f / fmaxf(sqrtf(ssq[dj]), 1e-12f);
      #pragma unroll
      for (int qi = 0; qi < 8; ++qi)
        outS[(long)(o8 + qi) * N + gd] = acc[qi][dj] * rn;  // coalesced
    }
  }
}

// ---------------- top-k helpers ----------------
// ranks-before comparator: higher score wins; tie -> smaller index (lax.top_k stable)
__device__ __forceinline__ void insert10(float v, float p, float bs[10], float bi[10]) {
  bool last = (v > bs[9]) || (v == bs[9] && p < bi[9]);
  if (!last) return;
  #pragma unroll
  for (int j = 9; j >= 1; --j) {     // static indices only (no scratch)
    bool bj  = (v > bs[j])   || (v == bs[j]   && p < bi[j]);
    bool bjm = (v > bs[j-1]) || (v == bs[j-1] && p < bi[j-1]);
    float ns = bj ? (bjm ? bs[j-1] : v) : bs[j];
    float ni = bj ? (bjm ? bi[j-1] : p) : bi[j];
    bs[j] = ns; bi[j] = ni;
  }
  bool b0 = (v > bs[0]) || (v == bs[0] && p < bi[0]);
  if (b0) { bs[0] = v; bi[0] = p; }
}

// ---------------- K4: per-(row, segment) top-10 ----------------
__global__ __launch_bounds__(256) void k_topblk(const float* __restrict__ scores,
                                                float2* __restrict__ btop, int N) {
  const int row = blockIdx.y, seg = blockIdx.x, t = threadIdx.x;
  const int per = (N + NBK - 1) / NBK;
  const int s0 = seg * per;
  const int s1 = (s0 + per < N) ? (s0 + per) : N;
  const float* rp = scores + (long)row * N;
  float bs[10], bi[10];
  #pragma unroll
  for (int k = 0; k < 10; ++k) { bs[k] = -INFINITY; bi[k] = 2.0e9f; }
  for (int p = s0 + t; p < s1; p += 256) insert10(rp[p], (float)p, bs, bi);

  __shared__ float ms[256][10];
  __shared__ float mi[256][10];
  #pragma unroll
  for (int k = 0; k < 10; ++k) { ms[t][k] = bs[k]; mi[t][k] = bi[k]; }
  __syncthreads();
  for (int h = 128; h > 0; h >>= 1) {
    if (t < h) {
      float os[10], oi[10];
      int x = 0, y = 0;
      #pragma unroll
      for (int k = 0; k < 10; ++k) {
        float sx = ms[t][x], sy = ms[t + h][y];
        float ix = mi[t][x], iy = mi[t + h][y];
        bool ta = (sx > sy) || (sx == sy && ix < iy);
        os[k] = ta ? sx : sy; oi[k] = ta ? ix : iy;
        x += ta ? 1 : 0; y += ta ? 0 : 1;
      }
      #pragma unroll
      for (int k = 0; k < 10; ++k) { ms[t][k] = os[k]; mi[t][k] = oi[k]; }
    }
    __syncthreads();
  }
  if (t == 0) {
    #pragma unroll
    for (int k = 0; k < 10; ++k)
      btop[((long)row * NBK + seg) * 10 + k] = make_float2(ms[0][k], mi[0][k]);
  }
}

// ---------------- K5: final merge per row, write indices as float ----------------
__global__ __launch_bounds__(256) void k_topfinal(const float2* __restrict__ btop,
                                                  float* __restrict__ outIdx) {
  const int row = blockIdx.x, t = threadIdx.x;
  const int M = NBK * 10;   // 640 candidates
  float bs[10], bi[10];
  #pragma unroll
  for (int k = 0; k < 10; ++k) { bs[k] = -INFINITY; bi[k] = 2.0e9f; }
  for (int p = t; p < M; p += 256) {
    float2 c = btop[(long)row * M + p];
    insert10(c.x, c.y, bs, bi);
  }
  __shared__ float ms[256][10];
  __shared__ float mi[256][10];
  #pragma unroll
  for (int k = 0; k < 10; ++k) { ms[t][k] = bs[k]; mi[t][k] = bi[k]; }
  __syncthreads();
  for (int h = 128; h > 0; h >>= 1) {
    if (t < h) {
      float os[10], oi[10];
      int x = 0, y = 0;
      #pragma unroll
      for (int k = 0; k < 10; ++k) {
        float sx = ms[t][x], sy = ms[t + h][y];
        float ix = mi[t][x], iy = mi[t + h][y];
        bool ta = (sx > sy) || (sx == sy && ix < iy);
        os[k] = ta ? sx : sy; oi[k] = ta ? ix : iy;
        x += ta ? 1 : 0; y += ta ? 0 : 1;
      }
      #pragma unroll
      for (int k = 0; k < 10; ++k) { ms[t][k] = os[k]; mi[t][k] = oi[k]; }
    }
    __syncthreads();
  }
  if (t == 0) {
    #pragma unroll
    for (int k = 0; k < 10; ++k) outIdx[row * TOPK + k] = mi[0][k];
  }
}

extern "C" void kernel_launch(void* const* d_in, const int* in_sizes, int n_in,
                              void* d_out, int out_size, void* d_ws, size_t ws_size,
                              hipStream_t stream) {
  const float* q    = (const float*)d_in[0];   // [32,128,768]
  const float* docs = (const float*)d_in[1];   // [N,768]
  const float* W    = (const float*)d_in[2];   // [768,768]
  const float* bias = (const float*)d_in[3];   // [768]
  const int B = in_sizes[0] / (SEQ * D);       // 32
  const int N = in_sizes[1] / D;               // 500000

  float* out    = (float*)d_out;
  float* outIdx = out;                          // [B*10] indices as float
  float* outS   = out + (long)B * TOPK;         // [B][N] scores

  float*  qmean = (float*)d_ws;                 // B*D
  float*  qnorm = qmean + (long)B * D;          // B*D
  float2* btop  = (float2*)(qnorm + (long)B * D); // B*NBK*10 pairs

  dim3 g1(3, B);
  k_mean<<<g1, 256, 0, stream>>>(q, qmean);
  k_proj<<<B, 256, 0, stream>>>(qmean, W, bias, qnorm);
  int ntiles = (N + TN - 1) / TN;
  k_scores<<<ntiles, 256, 0, stream>>>(docs, qnorm, outS, N);
  dim3 g4(NBK, B);
  k_topblk<<<g4, 256, 0, stream>>>(outS, btop, N);
  k_topfinal<<<B, 256, 0, stream>>>(btop, outIdx);
}